// Round 1
// baseline (474.804 us; speedup 1.0000x reference)
//
#include <hip/hip_runtime.h>

// ---------------------------------------------------------------------------
// 3-layer GCN: per layer  t = h@W + b ;  out[v] = sum_{e: dst[e]==v} w[e]*t[src[e]]
// Strategy: build CSR-by-dst on device (no fp atomics in the hot loop), then
// GEMM (W in LDS) + gather-aggregate (one block per node).
// ---------------------------------------------------------------------------

__global__ void hist_kernel(const int* __restrict__ dst, int* __restrict__ counts, int E) {
    int e = blockIdx.x * blockDim.x + threadIdx.x;
    if (e < E) atomicAdd(&counts[dst[e]], 1);
}

// Single-block exclusive scan over counts[N] -> row_ptr[N+1], cursor[N]=row_ptr[N]
// 1024 threads, 4 elements/thread/chunk, wave-shuffle scan (wave=64).
__global__ void scan_kernel(const int* __restrict__ counts, int* __restrict__ row_ptr,
                            int* __restrict__ cursor, int N, int E) {
    __shared__ int wsum[16];
    __shared__ int s_carry;
    if (threadIdx.x == 0) s_carry = 0;
    __syncthreads();
    const int lane = threadIdx.x & 63;
    const int wid  = threadIdx.x >> 6;   // 0..15
    for (int base = 0; base < N; base += 4096) {
        int idx = base + (int)threadIdx.x * 4;
        int4 c = {0, 0, 0, 0};
        if (idx + 3 < N) {
            c = *(const int4*)(counts + idx);
        } else {
            if (idx     < N) c.x = counts[idx];
            if (idx + 1 < N) c.y = counts[idx + 1];
            if (idx + 2 < N) c.z = counts[idx + 2];
        }
        int tsum = c.x + c.y + c.z + c.w;
        int val = tsum;  // inclusive wave scan
        #pragma unroll
        for (int off = 1; off < 64; off <<= 1) {
            int t = __shfl_up(val, off, 64);
            if (lane >= off) val += t;
        }
        if (lane == 63) wsum[wid] = val;
        __syncthreads();
        if (wid == 0) {
            int wv = (lane < 16) ? wsum[lane] : 0;
            #pragma unroll
            for (int off = 1; off < 16; off <<= 1) {
                int t = __shfl_up(wv, off, 64);
                if (lane >= off) wv += t;
            }
            if (lane < 16) wsum[lane] = wv;  // inclusive across waves
        }
        __syncthreads();
        int carry = s_carry;
        int total = wsum[15];
        int wbase = (wid == 0) ? 0 : wsum[wid - 1];
        int e0 = carry + wbase + (val - tsum);  // exclusive prefix of c.x
        int e1 = e0 + c.x, e2 = e1 + c.y, e3 = e2 + c.z;
        if (idx     < N) { row_ptr[idx]     = e0; cursor[idx]     = e0; }
        if (idx + 1 < N) { row_ptr[idx + 1] = e1; cursor[idx + 1] = e1; }
        if (idx + 2 < N) { row_ptr[idx + 2] = e2; cursor[idx + 2] = e2; }
        if (idx + 3 < N) { row_ptr[idx + 3] = e3; cursor[idx + 3] = e3; }
        __syncthreads();
        if (threadIdx.x == 0) s_carry = carry + total;
    }
    if (threadIdx.x == 0) row_ptr[N] = E;
}

__global__ void scatter_kernel(const int* __restrict__ src, const int* __restrict__ dst,
                               const float* __restrict__ w, int* __restrict__ cursor,
                               int* __restrict__ esrc, float* __restrict__ ew, int E) {
    int e = blockIdx.x * blockDim.x + threadIdx.x;
    if (e < E) {
        int d = dst[e];
        int p = atomicAdd(&cursor[d], 1);
        esrc[p] = src[e];
        ew[p]   = w[e];
    }
}

// T[n, M] = H[n, 128] @ Wm[128, M] + bias.  W staged in LDS; each thread owns a
// float4 of outputs for one node; NPB node-rows staged in LDS per iteration.
template <int M>
__global__ __launch_bounds__(256) void gemm_bias_kernel(const float* __restrict__ H,
                                                        const float* __restrict__ Wm,
                                                        const float* __restrict__ bias,
                                                        float* __restrict__ T, int N) {
    const int K = 128;
    const int TPN = M / 4;        // threads per node
    const int NPB = 256 / TPN;    // nodes per block per iter
    __shared__ float Wl[K * M];
    __shared__ float Hl[NPB * K];
    for (int i = threadIdx.x; i < K * M / 4; i += 256)
        ((float4*)Wl)[i] = ((const float4*)Wm)[i];
    const int fo = (threadIdx.x % TPN) * 4;
    const int nl = threadIdx.x / TPN;
    float4 bv = *(const float4*)(bias + fo);
    for (int node0 = blockIdx.x * NPB; node0 < N; node0 += gridDim.x * NPB) {
        __syncthreads();  // (also covers the Wl load on the first pass)
        for (int i = threadIdx.x; i < NPB * K / 4; i += 256) {
            int r = i / (K / 4), c = i % (K / 4);
            int node = node0 + r;
            float4 hv = {0, 0, 0, 0};
            if (node < N) hv = ((const float4*)(H + (size_t)node * K))[c];
            ((float4*)Hl)[i] = hv;
        }
        __syncthreads();
        float4 acc = bv;
        const float* hr = Hl + nl * K;
        #pragma unroll 4
        for (int k = 0; k < K; k++) {
            float hv = hr[k];
            float4 wv = *(const float4*)(Wl + k * M + fo);
            acc.x = fmaf(hv, wv.x, acc.x);
            acc.y = fmaf(hv, wv.y, acc.y);
            acc.z = fmaf(hv, wv.z, acc.z);
            acc.w = fmaf(hv, wv.w, acc.w);
        }
        int node = node0 + nl;
        if (node < N) *(float4*)(T + (size_t)node * M + fo) = acc;
    }
}

// One block per destination node; thread f accumulates feature f over the
// node's CSR edge range. Unroll-by-2 for two row-loads in flight.
template <int M, bool RELU>
__global__ void agg_kernel(const float* __restrict__ T, const int* __restrict__ row_ptr,
                           const int* __restrict__ esrc, const float* __restrict__ ew,
                           float* __restrict__ OUT, int N) {
    int v = blockIdx.x;
    int f = threadIdx.x;
    int beg = row_ptr[v], end = row_ptr[v + 1];
    float acc = 0.f;
    int i = beg;
    for (; i + 1 < end; i += 2) {
        int   s0 = esrc[i],  s1 = esrc[i + 1];
        float w0 = ew[i],    w1 = ew[i + 1];
        float t0 = T[(size_t)s0 * M + f];
        float t1 = T[(size_t)s1 * M + f];
        acc = fmaf(w0, t0, acc);
        acc = fmaf(w1, t1, acc);
    }
    if (i < end) acc = fmaf(ew[i], T[(size_t)esrc[i] * M + f], acc);
    if (RELU) acc = fmaxf(acc, 0.f);
    OUT[(size_t)v * M + f] = acc;
}

extern "C" void kernel_launch(void* const* d_in, const int* in_sizes, int n_in,
                              void* d_out, int out_size, void* d_ws, size_t ws_size,
                              hipStream_t stream) {
    const float* x   = (const float*)d_in[0];
    const float* w   = (const float*)d_in[1];
    const int*   src = (const int*)d_in[2];
    const int*   dst = (const int*)d_in[3];
    const float* W1  = (const float*)d_in[4];
    const float* b1  = (const float*)d_in[5];
    const float* W2  = (const float*)d_in[6];
    const float* b2  = (const float*)d_in[7];
    const float* W3  = (const float*)d_in[8];
    const float* b3  = (const float*)d_in[9];
    const int N = in_sizes[0] / 128;   // 50000
    const int E = in_sizes[1];         // 600000

    // Workspace layout (all 16B-aligned where vector-accessed):
    float* bufA   = (float*)d_ws;                 // N*128 floats
    float* bufB   = bufA + (size_t)N * 128;       // N*128 floats
    float* ew     = bufB + (size_t)N * 128;       // E floats
    int*   esrc   = (int*)(ew + E);               // E ints
    int*   counts = esrc + E;                     // N ints (16B-aligned)
    int*   row_ptr= counts + N;                   // N+1 ints
    int*   cursor = row_ptr + N + 1;              // N ints

    // --- build CSR by destination ---
    hipMemsetAsync(counts, 0, (size_t)N * sizeof(int), stream);
    hist_kernel<<<(E + 255) / 256, 256, 0, stream>>>(dst, counts, E);
    scan_kernel<<<1, 1024, 0, stream>>>(counts, row_ptr, cursor, N, E);
    scatter_kernel<<<(E + 255) / 256, 256, 0, stream>>>(src, dst, w, cursor, esrc, ew, E);

    // --- layer 1 ---
    gemm_bias_kernel<128><<<(N + 7) / 8, 256, 0, stream>>>(x, W1, b1, bufA, N);
    agg_kernel<128, true><<<N, 128, 0, stream>>>(bufA, row_ptr, esrc, ew, bufB, N);
    // --- layer 2 ---
    gemm_bias_kernel<128><<<(N + 7) / 8, 256, 0, stream>>>(bufB, W2, b2, bufA, N);
    agg_kernel<128, true><<<N, 128, 0, stream>>>(bufA, row_ptr, esrc, ew, bufB, N);
    // --- layer 3 (transform first: aggregate at width 64, half the gather bytes) ---
    gemm_bias_kernel<64><<<(N + 15) / 16, 256, 0, stream>>>(bufB, W3, b3, bufA, N);
    agg_kernel<64, false><<<N, 64, 0, stream>>>(bufA, row_ptr, esrc, ew, (float*)d_out, N);
}

// Round 2
// 421.404 us; speedup vs baseline: 1.1267x; 1.1267x over previous
//
#include <hip/hip_runtime.h>

// ---------------------------------------------------------------------------
// 3-layer GCN: per layer  t = h@W + b ;  out[v] = sum_{e: dst[e]==v} w[e]*t[src[e]]
// CSR-by-dst built on device, then register-tiled GEMM + wave-per-node gather.
// ---------------------------------------------------------------------------

__global__ void hist_kernel(const int* __restrict__ dst, int* __restrict__ counts, int E) {
    int e = blockIdx.x * blockDim.x + threadIdx.x;
    if (e < E) atomicAdd(&counts[dst[e]], 1);
}

// Single-block exclusive scan over counts[N] -> row_ptr[N+1], cursor[N]=row_ptr[N]
__global__ void scan_kernel(const int* __restrict__ counts, int* __restrict__ row_ptr,
                            int* __restrict__ cursor, int N, int E) {
    __shared__ int wsum[16];
    __shared__ int s_carry;
    if (threadIdx.x == 0) s_carry = 0;
    __syncthreads();
    const int lane = threadIdx.x & 63;
    const int wid  = threadIdx.x >> 6;   // 0..15
    for (int base = 0; base < N; base += 4096) {
        int idx = base + (int)threadIdx.x * 4;
        int4 c = {0, 0, 0, 0};
        if (idx + 3 < N) {
            c = *(const int4*)(counts + idx);
        } else {
            if (idx     < N) c.x = counts[idx];
            if (idx + 1 < N) c.y = counts[idx + 1];
            if (idx + 2 < N) c.z = counts[idx + 2];
        }
        int tsum = c.x + c.y + c.z + c.w;
        int val = tsum;  // inclusive wave scan
        #pragma unroll
        for (int off = 1; off < 64; off <<= 1) {
            int t = __shfl_up(val, off, 64);
            if (lane >= off) val += t;
        }
        if (lane == 63) wsum[wid] = val;
        __syncthreads();
        if (wid == 0) {
            int wv = (lane < 16) ? wsum[lane] : 0;
            #pragma unroll
            for (int off = 1; off < 16; off <<= 1) {
                int t = __shfl_up(wv, off, 64);
                if (lane >= off) wv += t;
            }
            if (lane < 16) wsum[lane] = wv;  // inclusive across waves
        }
        __syncthreads();
        int carry = s_carry;
        int total = wsum[15];
        int wbase = (wid == 0) ? 0 : wsum[wid - 1];
        int e0 = carry + wbase + (val - tsum);
        int e1 = e0 + c.x, e2 = e1 + c.y, e3 = e2 + c.z;
        if (idx     < N) { row_ptr[idx]     = e0; cursor[idx]     = e0; }
        if (idx + 1 < N) { row_ptr[idx + 1] = e1; cursor[idx + 1] = e1; }
        if (idx + 2 < N) { row_ptr[idx + 2] = e2; cursor[idx + 2] = e2; }
        if (idx + 3 < N) { row_ptr[idx + 3] = e3; cursor[idx + 3] = e3; }
        __syncthreads();
        if (threadIdx.x == 0) s_carry = carry + total;
    }
    if (threadIdx.x == 0) row_ptr[N] = E;
}

__global__ void scatter_kernel(const int* __restrict__ src, const int* __restrict__ dst,
                               const float* __restrict__ w, int* __restrict__ cursor,
                               int* __restrict__ esrc, float* __restrict__ ew, int E) {
    int e = blockIdx.x * blockDim.x + threadIdx.x;
    if (e < E) {
        int d = dst[e];
        int p = atomicAdd(&cursor[d], 1);
        esrc[p] = src[e];
        ew[p]   = w[e];
    }
}

// T[n, M] = H[n, 128] @ Wm[128, M] + bias.
// Register tile: each thread computes 4 nodes x 4 feats.  Per k-step:
// 1 ds_read_b128 (W) + 4 lane-uniform ds_read_b32 (H broadcast, conflict-free)
// feeding 16 FMAs -> VALU-limited, not LDS-limited.
// LDS: W (K*M*4 B) + H tile (NT*128*4 B, unpadded; 2-way alias is free).
template <int M, int NT>
__global__ __launch_bounds__(256, 2) void gemm_v2(const float* __restrict__ H,
                                                  const float* __restrict__ Wm,
                                                  const float* __restrict__ bias,
                                                  float* __restrict__ T, int N) {
    const int K = 128;
    __shared__ float Wl[K * M];
    __shared__ float Hl[NT * K];
    const int FG = M / 4;                 // f-groups per node row
    const int fg = threadIdx.x % FG;
    const int ng = threadIdx.x / FG;      // node group (4 nodes each)
    const int fo = fg * 4;
    const int n0 = ng * 4;

    for (int i = threadIdx.x; i < K * M / 4; i += 256)
        ((float4*)Wl)[i] = ((const float4*)Wm)[i];

    const int node0 = blockIdx.x * NT;
    for (int i = threadIdx.x; i < NT * K / 4; i += 256) {
        int r = i / (K / 4), c = i % (K / 4);
        int node = node0 + r;
        float4 hv = {0, 0, 0, 0};
        if (node < N) hv = ((const float4*)(H + (size_t)node * K))[c];
        ((float4*)(Hl + r * K))[c] = hv;
    }
    __syncthreads();

    float4 bv = *(const float4*)(bias + fo);
    float4 acc0 = bv, acc1 = bv, acc2 = bv, acc3 = bv;
    const float* h0 = Hl + (n0 + 0) * K;
    const float* h1 = Hl + (n0 + 1) * K;
    const float* h2 = Hl + (n0 + 2) * K;
    const float* h3 = Hl + (n0 + 3) * K;
    #pragma unroll 4
    for (int k = 0; k < K; k++) {
        float4 wv = *(const float4*)(Wl + k * M + fo);
        float a = h0[k], b = h1[k], c = h2[k], d = h3[k];
        acc0.x = fmaf(a, wv.x, acc0.x); acc0.y = fmaf(a, wv.y, acc0.y);
        acc0.z = fmaf(a, wv.z, acc0.z); acc0.w = fmaf(a, wv.w, acc0.w);
        acc1.x = fmaf(b, wv.x, acc1.x); acc1.y = fmaf(b, wv.y, acc1.y);
        acc1.z = fmaf(b, wv.z, acc1.z); acc1.w = fmaf(b, wv.w, acc1.w);
        acc2.x = fmaf(c, wv.x, acc2.x); acc2.y = fmaf(c, wv.y, acc2.y);
        acc2.z = fmaf(c, wv.z, acc2.z); acc2.w = fmaf(c, wv.w, acc2.w);
        acc3.x = fmaf(d, wv.x, acc3.x); acc3.y = fmaf(d, wv.y, acc3.y);
        acc3.z = fmaf(d, wv.z, acc3.z); acc3.w = fmaf(d, wv.w, acc3.w);
    }
    int nb = node0 + n0;
    if (nb + 0 < N) *(float4*)(T + (size_t)(nb + 0) * M + fo) = acc0;
    if (nb + 1 < N) *(float4*)(T + (size_t)(nb + 1) * M + fo) = acc1;
    if (nb + 2 < N) *(float4*)(T + (size_t)(nb + 2) * M + fo) = acc2;
    if (nb + 3 < N) *(float4*)(T + (size_t)(nb + 3) * M + fo) = acc3;
}

// Wave-per-node aggregation.  M=128: lane owns float2 -> one dwordx2
// wave-instr fetches a full 512 B source row.  M=64: lane owns one float.
template <int M, bool RELU>
__global__ void agg_v2(const float* __restrict__ T, const int* __restrict__ row_ptr,
                       const int* __restrict__ esrc, const float* __restrict__ ew,
                       float* __restrict__ OUT, int N) {
    const int wid  = threadIdx.x >> 6;
    const int lane = threadIdx.x & 63;
    const int v = blockIdx.x * 4 + wid;
    if (v >= N) return;
    const int beg = row_ptr[v], end = row_ptr[v + 1];
    if (M == 128) {
        const int fo = lane * 2;
        float2 acc = {0.f, 0.f};
        int i = beg;
        for (; i + 1 < end; i += 2) {
            int   s0 = esrc[i],  s1 = esrc[i + 1];
            float w0 = ew[i],    w1 = ew[i + 1];
            float2 t0 = *(const float2*)(T + (size_t)s0 * M + fo);
            float2 t1 = *(const float2*)(T + (size_t)s1 * M + fo);
            acc.x = fmaf(w0, t0.x, acc.x); acc.y = fmaf(w0, t0.y, acc.y);
            acc.x = fmaf(w1, t1.x, acc.x); acc.y = fmaf(w1, t1.y, acc.y);
        }
        if (i < end) {
            float w0 = ew[i];
            float2 t0 = *(const float2*)(T + (size_t)esrc[i] * M + fo);
            acc.x = fmaf(w0, t0.x, acc.x); acc.y = fmaf(w0, t0.y, acc.y);
        }
        if (RELU) { acc.x = fmaxf(acc.x, 0.f); acc.y = fmaxf(acc.y, 0.f); }
        *(float2*)(OUT + (size_t)v * M + fo) = acc;
    } else {
        const int fo = lane;
        float acc = 0.f;
        int i = beg;
        for (; i + 1 < end; i += 2) {
            int   s0 = esrc[i],  s1 = esrc[i + 1];
            float w0 = ew[i],    w1 = ew[i + 1];
            float t0 = T[(size_t)s0 * M + fo];
            float t1 = T[(size_t)s1 * M + fo];
            acc = fmaf(w0, t0, acc);
            acc = fmaf(w1, t1, acc);
        }
        if (i < end) acc = fmaf(ew[i], T[(size_t)esrc[i] * M + fo], acc);
        if (RELU) acc = fmaxf(acc, 0.f);
        OUT[(size_t)v * M + fo] = acc;
    }
}

extern "C" void kernel_launch(void* const* d_in, const int* in_sizes, int n_in,
                              void* d_out, int out_size, void* d_ws, size_t ws_size,
                              hipStream_t stream) {
    const float* x   = (const float*)d_in[0];
    const float* w   = (const float*)d_in[1];
    const int*   src = (const int*)d_in[2];
    const int*   dst = (const int*)d_in[3];
    const float* W1  = (const float*)d_in[4];
    const float* b1  = (const float*)d_in[5];
    const float* W2  = (const float*)d_in[6];
    const float* b2  = (const float*)d_in[7];
    const float* W3  = (const float*)d_in[8];
    const float* b3  = (const float*)d_in[9];
    const int N = in_sizes[0] / 128;   // 50000
    const int E = in_sizes[1];         // 600000

    float* bufA    = (float*)d_ws;                 // N*128 floats
    float* bufB    = bufA + (size_t)N * 128;       // N*128 floats
    float* ew      = bufB + (size_t)N * 128;       // E floats
    int*   esrc    = (int*)(ew + E);               // E ints
    int*   counts  = esrc + E;                     // N ints
    int*   row_ptr = counts + N;                   // N+1 ints
    int*   cursor  = row_ptr + N + 1;              // N ints

    // --- build CSR by destination ---
    hipMemsetAsync(counts, 0, (size_t)N * sizeof(int), stream);
    hist_kernel<<<(E + 255) / 256, 256, 0, stream>>>(dst, counts, E);
    scan_kernel<<<1, 1024, 0, stream>>>(counts, row_ptr, cursor, N, E);
    scatter_kernel<<<(E + 255) / 256, 256, 0, stream>>>(src, dst, w, cursor, esrc, ew, E);

    // --- layer 1 ---
    gemm_v2<128, 32><<<(N + 31) / 32, 256, 0, stream>>>(x, W1, b1, bufA, N);
    agg_v2<128, true><<<(N + 3) / 4, 256, 0, stream>>>(bufA, row_ptr, esrc, ew, bufB, N);
    // --- layer 2 ---
    gemm_v2<128, 32><<<(N + 31) / 32, 256, 0, stream>>>(bufB, W2, b2, bufA, N);
    agg_v2<128, true><<<(N + 3) / 4, 256, 0, stream>>>(bufA, row_ptr, esrc, ew, bufB, N);
    // --- layer 3 (transform first: aggregate at width 64, half the gather bytes) ---
    gemm_v2<64, 64><<<(N + 63) / 64, 256, 0, stream>>>(bufB, W3, b3, bufA, N);
    agg_v2<64, false><<<(N + 3) / 4, 256, 0, stream>>>(bufA, row_ptr, esrc, ew, (float*)d_out, N);
}

// Round 3
// 359.624 us; speedup vs baseline: 1.3203x; 1.1718x over previous
//
#include <hip/hip_runtime.h>

// ---------------------------------------------------------------------------
// 3-layer GCN:  t = h@W + b ;  out[v] = sum_{e: dst[e]==v} w[e]*t[src[e]]
// CSR-by-dst on device; GEMM via split-bf16 MFMA (3-term, ~fp32 accuracy);
// T stored bf16 to halve aggregation gather traffic.
// ---------------------------------------------------------------------------

typedef __attribute__((ext_vector_type(8))) short short8;
typedef __attribute__((ext_vector_type(4))) float float4v;

__device__ inline unsigned bf16_rne(float f) {
    unsigned u = __float_as_uint(f);
    return (u + 0x7FFF + ((u >> 16) & 1)) >> 16;
}

// ---------------- CSR build ----------------
__global__ void hist_kernel(const int* __restrict__ dst, int* __restrict__ counts, int E) {
    int e = blockIdx.x * blockDim.x + threadIdx.x;
    if (e < E) atomicAdd(&counts[dst[e]], 1);
}

__global__ void scan_kernel(const int* __restrict__ counts, int* __restrict__ row_ptr,
                            int* __restrict__ cursor, int N, int E) {
    __shared__ int wsum[16];
    __shared__ int s_carry;
    if (threadIdx.x == 0) s_carry = 0;
    __syncthreads();
    const int lane = threadIdx.x & 63;
    const int wid  = threadIdx.x >> 6;
    for (int base = 0; base < N; base += 4096) {
        int idx = base + (int)threadIdx.x * 4;
        int4 c = {0, 0, 0, 0};
        if (idx + 3 < N) {
            c = *(const int4*)(counts + idx);
        } else {
            if (idx     < N) c.x = counts[idx];
            if (idx + 1 < N) c.y = counts[idx + 1];
            if (idx + 2 < N) c.z = counts[idx + 2];
        }
        int tsum = c.x + c.y + c.z + c.w;
        int val = tsum;
        #pragma unroll
        for (int off = 1; off < 64; off <<= 1) {
            int t = __shfl_up(val, off, 64);
            if (lane >= off) val += t;
        }
        if (lane == 63) wsum[wid] = val;
        __syncthreads();
        if (wid == 0) {
            int wv = (lane < 16) ? wsum[lane] : 0;
            #pragma unroll
            for (int off = 1; off < 16; off <<= 1) {
                int t = __shfl_up(wv, off, 64);
                if (lane >= off) wv += t;
            }
            if (lane < 16) wsum[lane] = wv;
        }
        __syncthreads();
        int carry = s_carry;
        int total = wsum[15];
        int wbase = (wid == 0) ? 0 : wsum[wid - 1];
        int e0 = carry + wbase + (val - tsum);
        int e1 = e0 + c.x, e2 = e1 + c.y, e3 = e2 + c.z;
        if (idx     < N) { row_ptr[idx]     = e0; cursor[idx]     = e0; }
        if (idx + 1 < N) { row_ptr[idx + 1] = e1; cursor[idx + 1] = e1; }
        if (idx + 2 < N) { row_ptr[idx + 2] = e2; cursor[idx + 2] = e2; }
        if (idx + 3 < N) { row_ptr[idx + 3] = e3; cursor[idx + 3] = e3; }
        __syncthreads();
        if (threadIdx.x == 0) s_carry = carry + total;
    }
    if (threadIdx.x == 0) row_ptr[N] = E;
}

__global__ void scatter_kernel(const int* __restrict__ src, const int* __restrict__ dst,
                               const float* __restrict__ w, int* __restrict__ cursor,
                               int* __restrict__ esrc, float* __restrict__ ew, int E) {
    int e = blockIdx.x * blockDim.x + threadIdx.x;
    if (e < E) {
        int d = dst[e];
        int p = atomicAdd(&cursor[d], 1);
        esrc[p] = src[e];
        ew[p]   = w[e];
    }
}

// ---------------- W fragment prep (hi/lo bf16, B-frag order) ----------------
// B-frag (16x16x32): element j of lane l = B[k = ks*32 + (l>>4)*8 + j][n = ft*16 + (l&15)]
// Stored flat: idx = ((ks*FT + ft)*64 + lane)*8 + j
template <int M>
__global__ void wprep_kernel(const float* __restrict__ Wm,
                             unsigned short* __restrict__ WfH,
                             unsigned short* __restrict__ WfL) {
    const int FT = M / 16;
    int t = blockIdx.x * blockDim.x + threadIdx.x;
    if (t >= 4 * FT * 64) return;
    int lane = t & 63;
    int ft   = (t >> 6) % FT;
    int ks   = t / (64 * FT);
    int n     = ft * 16 + (lane & 15);
    int kbase = ks * 32 + (lane >> 4) * 8;
    #pragma unroll
    for (int j = 0; j < 8; j++) {
        float wv = Wm[(size_t)(kbase + j) * M + n];
        unsigned hb = bf16_rne(wv);
        float wh = __uint_as_float(hb << 16);
        unsigned lb = bf16_rne(wv - wh);
        WfH[(size_t)t * 8 + j] = (unsigned short)hb;
        WfL[(size_t)t * 8 + j] = (unsigned short)lb;
    }
}

// ---------------- MFMA GEMM:  T(bf16)[n, M] = H(f32)[n,128] @ W + b ----------
// Block = 256 (4 waves), 64 nodes/block (16 per wave).  Split-bf16 3-term:
// D = Ah*Bh + Al*Bh + Ah*Bl  (error ~ Al*Bl ~ 2^-15 relative).
// Wh frags staged in LDS (conflict-free b128); Wl frags read from global (L1/L2-hot).
template <int M>
__global__ __launch_bounds__(256) void gemm_mfma(const float* __restrict__ H,
                                                 const unsigned short* __restrict__ WfH,
                                                 const unsigned short* __restrict__ WfL,
                                                 const float* __restrict__ bias,
                                                 unsigned short* __restrict__ T, int N) {
    const int K  = 128;
    const int KP = K + 4;          // +16B pad: frag reads land 2-way max (free)
    const int FT = M / 16;
    __shared__ float Hs[64 * KP];
    __shared__ __align__(16) unsigned short Ws[4 * FT * 64 * 8];

    const int node0 = blockIdx.x * 64;
    for (int i = threadIdx.x; i < 64 * (K / 4); i += 256) {
        int r = i / (K / 4), c = i % (K / 4);
        int node = node0 + r;
        float4 hv = {0, 0, 0, 0};
        if (node < N) hv = ((const float4*)(H + (size_t)node * K))[c];
        *(float4*)(Hs + r * KP + c * 4) = hv;
    }
    const int WSH = 4 * FT * 64;   // in short8 units
    for (int i = threadIdx.x; i < WSH; i += 256)
        ((short8*)Ws)[i] = ((const short8*)WfH)[i];
    __syncthreads();

    const int wave = threadIdx.x >> 6;
    const int lane = threadIdx.x & 63;
    const int row  = lane & 15;
    const int ksub = (lane >> 4) * 8;
    const float* hrow = Hs + (wave * 16 + row) * KP;

    float4v acc[FT];
    #pragma unroll
    for (int ft = 0; ft < FT; ft++) acc[ft] = (float4v){0.f, 0.f, 0.f, 0.f};

    #pragma unroll
    for (int ks = 0; ks < 4; ks++) {
        const float* ap = hrow + ks * 32 + ksub;
        float4 a0 = *(const float4*)(ap);
        float4 a1 = *(const float4*)(ap + 4);
        float av[8] = {a0.x, a0.y, a0.z, a0.w, a1.x, a1.y, a1.z, a1.w};
        short8 ah, al;
        #pragma unroll
        for (int j = 0; j < 8; j++) {
            unsigned hb = bf16_rne(av[j]);
            float fh = __uint_as_float(hb << 16);
            unsigned lb = bf16_rne(av[j] - fh);
            ah[j] = (short)hb;
            al[j] = (short)lb;
        }
        #pragma unroll
        for (int ft = 0; ft < FT; ft++) {
            short8 bh = *(const short8*)(Ws + ((ks * FT + ft) * 64 + lane) * 8);
            short8 bl = *(const short8*)(WfL + ((size_t)(ks * FT + ft) * 64 + lane) * 8);
            acc[ft] = __builtin_amdgcn_mfma_f32_16x16x32_bf16(ah, bh, acc[ft], 0, 0, 0);
            acc[ft] = __builtin_amdgcn_mfma_f32_16x16x32_bf16(al, bh, acc[ft], 0, 0, 0);
            acc[ft] = __builtin_amdgcn_mfma_f32_16x16x32_bf16(ah, bl, acc[ft], 0, 0, 0);
        }
    }

    // C/D: col = lane&15, row = (lane>>4)*4 + reg
    const int col   = lane & 15;
    const int rbase = (lane >> 4) * 4;
    #pragma unroll
    for (int ft = 0; ft < FT; ft++) {
        int feat = ft * 16 + col;
        float bv = bias[feat];
        #pragma unroll
        for (int r = 0; r < 4; r++) {
            int node = node0 + wave * 16 + rbase + r;
            if (node < N)
                T[(size_t)node * M + feat] = (unsigned short)bf16_rne(acc[ft][r] + bv);
        }
    }
}

// ---------------- Aggregation: wave per node, bf16 T rows ----------------
template <int M, bool RELU>
__global__ void agg_v3(const unsigned short* __restrict__ T, const int* __restrict__ row_ptr,
                       const int* __restrict__ esrc, const float* __restrict__ ew,
                       float* __restrict__ OUT, int N) {
    const int wid  = threadIdx.x >> 6;
    const int lane = threadIdx.x & 63;
    const int v = blockIdx.x * 4 + wid;
    if (v >= N) return;
    const int beg = row_ptr[v], end = row_ptr[v + 1];
    if (M == 128) {
        const int fo = lane * 2;
        float ax = 0.f, ay = 0.f;
        int i = beg;
        for (; i + 3 < end; i += 4) {
            int   s0 = esrc[i],     s1 = esrc[i + 1], s2 = esrc[i + 2], s3 = esrc[i + 3];
            float w0 = ew[i],       w1 = ew[i + 1],   w2 = ew[i + 2],   w3 = ew[i + 3];
            unsigned t0 = *(const unsigned*)(T + (size_t)s0 * M + fo);
            unsigned t1 = *(const unsigned*)(T + (size_t)s1 * M + fo);
            unsigned t2 = *(const unsigned*)(T + (size_t)s2 * M + fo);
            unsigned t3 = *(const unsigned*)(T + (size_t)s3 * M + fo);
            ax = fmaf(w0, __uint_as_float(t0 << 16), ax);
            ay = fmaf(w0, __uint_as_float(t0 & 0xFFFF0000u), ay);
            ax = fmaf(w1, __uint_as_float(t1 << 16), ax);
            ay = fmaf(w1, __uint_as_float(t1 & 0xFFFF0000u), ay);
            ax = fmaf(w2, __uint_as_float(t2 << 16), ax);
            ay = fmaf(w2, __uint_as_float(t2 & 0xFFFF0000u), ay);
            ax = fmaf(w3, __uint_as_float(t3 << 16), ax);
            ay = fmaf(w3, __uint_as_float(t3 & 0xFFFF0000u), ay);
        }
        for (; i < end; i++) {
            float w0 = ew[i];
            unsigned t0 = *(const unsigned*)(T + (size_t)esrc[i] * M + fo);
            ax = fmaf(w0, __uint_as_float(t0 << 16), ax);
            ay = fmaf(w0, __uint_as_float(t0 & 0xFFFF0000u), ay);
        }
        if (RELU) { ax = fmaxf(ax, 0.f); ay = fmaxf(ay, 0.f); }
        float2 o = {ax, ay};
        *(float2*)(OUT + (size_t)v * M + fo) = o;
    } else {
        float acc = 0.f;
        int i = beg;
        for (; i + 3 < end; i += 4) {
            int   s0 = esrc[i],     s1 = esrc[i + 1], s2 = esrc[i + 2], s3 = esrc[i + 3];
            float w0 = ew[i],       w1 = ew[i + 1],   w2 = ew[i + 2],   w3 = ew[i + 3];
            float t0 = __uint_as_float((unsigned)T[(size_t)s0 * M + lane] << 16);
            float t1 = __uint_as_float((unsigned)T[(size_t)s1 * M + lane] << 16);
            float t2 = __uint_as_float((unsigned)T[(size_t)s2 * M + lane] << 16);
            float t3 = __uint_as_float((unsigned)T[(size_t)s3 * M + lane] << 16);
            acc = fmaf(w0, t0, acc); acc = fmaf(w1, t1, acc);
            acc = fmaf(w2, t2, acc); acc = fmaf(w3, t3, acc);
        }
        for (; i < end; i++)
            acc = fmaf(ew[i], __uint_as_float((unsigned)T[(size_t)esrc[i] * M + lane] << 16), acc);
        if (RELU) acc = fmaxf(acc, 0.f);
        OUT[(size_t)v * M + lane] = acc;
    }
}

extern "C" void kernel_launch(void* const* d_in, const int* in_sizes, int n_in,
                              void* d_out, int out_size, void* d_ws, size_t ws_size,
                              hipStream_t stream) {
    const float* x   = (const float*)d_in[0];
    const float* w   = (const float*)d_in[1];
    const int*   src = (const int*)d_in[2];
    const int*   dst = (const int*)d_in[3];
    const float* W1  = (const float*)d_in[4];
    const float* b1  = (const float*)d_in[5];
    const float* W2  = (const float*)d_in[6];
    const float* b2  = (const float*)d_in[7];
    const float* W3  = (const float*)d_in[8];
    const float* b3  = (const float*)d_in[9];
    const int N = in_sizes[0] / 128;   // 50000
    const int E = in_sizes[1];         // 600000

    // Workspace layout (floats unless noted; all 16B-aligned by construction)
    float* bufB    = (float*)d_ws;                       // N*128 f32 (agg out / gemm in)
    unsigned short* Tbf = (unsigned short*)(bufB + (size_t)N * 128);  // N*128 bf16
    float* ew      = (float*)(Tbf + (size_t)N * 128);    // E f32
    int*   esrc    = (int*)(ew + E);                     // E
    int*   counts  = esrc + E;                           // N
    int*   row_ptr = counts + N;                         // N+1
    int*   cursor  = row_ptr + N + 1;                    // N
    // pad to 16B boundary for frag tables
    size_t off = (size_t)(cursor + N - (int*)d_ws);
    off = (off + 3) & ~(size_t)3;                        // in 4B units, 16B align
    unsigned short* WfH1 = (unsigned short*)((int*)d_ws + off);   // 128*128 shorts
    unsigned short* WfL1 = WfH1 + 128 * 128;
    unsigned short* WfH2 = WfL1 + 128 * 128;
    unsigned short* WfL2 = WfH2 + 128 * 128;
    unsigned short* WfH3 = WfL2 + 128 * 128;             // 128*64 shorts
    unsigned short* WfL3 = WfH3 + 128 * 64;

    // --- CSR build ---
    hipMemsetAsync(counts, 0, (size_t)N * sizeof(int), stream);
    hist_kernel<<<(E + 255) / 256, 256, 0, stream>>>(dst, counts, E);
    scan_kernel<<<1, 1024, 0, stream>>>(counts, row_ptr, cursor, N, E);
    scatter_kernel<<<(E + 255) / 256, 256, 0, stream>>>(src, dst, w, cursor, esrc, ew, E);

    // --- W fragment prep ---
    wprep_kernel<128><<<8, 256, 0, stream>>>(W1, WfH1, WfL1);
    wprep_kernel<128><<<8, 256, 0, stream>>>(W2, WfH2, WfL2);
    wprep_kernel<64><<<4, 256, 0, stream>>>(W3, WfH3, WfL3);

    const int GB = (N + 63) / 64;   // gemm blocks
    // --- layer 1 ---
    gemm_mfma<128><<<GB, 256, 0, stream>>>(x, WfH1, WfL1, b1, Tbf, N);
    agg_v3<128, true><<<(N + 3) / 4, 256, 0, stream>>>(Tbf, row_ptr, esrc, ew, bufB, N);
    // --- layer 2 ---
    gemm_mfma<128><<<GB, 256, 0, stream>>>(bufB, WfH2, WfL2, b2, Tbf, N);
    agg_v3<128, true><<<(N + 3) / 4, 256, 0, stream>>>(Tbf, row_ptr, esrc, ew, bufB, N);
    // --- layer 3 (transform first: aggregate at width 64) ---
    gemm_mfma<64><<<GB, 256, 0, stream>>>(bufB, WfH3, WfL3, b3, Tbf, N);
    agg_v3<64, false><<<(N + 3) / 4, 256, 0, stream>>>(Tbf, row_ptr, esrc, ew, (float*)d_out, N);
}